// Round 13
// baseline (94.538 us; speedup 1.0000x reference)
//
#include <hip/hip_runtime.h>
#include <math.h>

typedef float f4_t __attribute__((ext_vector_type(4)));

#define NTERM 20           // Taylor powers T_0..T_19 of Z=-iH (||Z||<=4 -> err ~5e-7)
#define TROW  9            // padded row stride (float2) inside one T matrix
#define TMAT  (TROW * 8)   // float2 per stored matrix

__device__ const float INVFACT[48] = {
  1.0f, 1.0f, 5.0e-1f, 1.66666666666667e-1f, 4.16666666666667e-2f,
  8.33333333333333e-3f, 1.38888888888889e-3f, 1.98412698412698e-4f,
  2.48015873015873e-5f, 2.75573192239859e-6f, 2.75573192239859e-7f,
  2.50521083854417e-8f, 2.08767569878681e-9f, 1.60590438368216e-10f,
  1.14707455977297e-11f, 7.64716373181982e-13f, 4.77947733238738e-14f,
  2.81145725434552e-15f, 1.56192069685862e-16f, 8.22063524662433e-18f,
  4.11031762331216e-19f, 1.95729410633913e-20f, 8.89679139245057e-22f,
  3.86817017063068e-23f, 1.61173757109612e-24f, 6.44695028438447e-26f,
  2.47959626322480e-27f, 9.18368986379555e-29f, 3.27988923706984e-30f,
  1.13099628864477e-31f, 3.76998762881591e-33f, 1.21612504155352e-34f,
  3.80039075485474e-36f, 1.15163356207720e-37f, 3.38715753552116e-39f,
  0.f, 0.f, 0.f, 0.f, 0.f, 0.f, 0.f, 0.f, 0.f, 0.f, 0.f, 0.f, 0.f
};

__device__ __forceinline__ double rdin(const void* p, int idx, bool isdbl) {
  return isdbl ? ((const double*)p)[idx] : (double)((const float*)p)[idx];
}

__device__ __forceinline__ float bpf(int srcl, float v) {
  return __int_as_float(__builtin_amdgcn_ds_bpermute(srcl, __float_as_int(v)));
}

// C = A*B, 8x8 complex, lane-distributed (lane r*8+c holds element [r][c]).
__device__ __forceinline__ void gmul(float& Cr, float& Ci,
                                     float Ar, float Ai, float Br, float Bi,
                                     int r, int c) {
  float nr = 0.f, ni = 0.f;
  #pragma unroll
  for (int u = 0; u < 8; ++u) {
    int sa = ((r << 3) | u) << 2;
    int sb = ((u << 3) | c) << 2;
    float ar = bpf(sa, Ar), ai = bpf(sa, Ai);
    float br = bpf(sb, Br), bi = bpf(sb, Bi);
    nr += ar*br - ai*bi;
    ni += ar*bi + ai*br;
  }
  Cr = nr; Ci = ni;
}

// C = Z*B with Z's row cached in registers (Zrow[u] = Z[r][u]).
__device__ __forceinline__ void zmul(float& Cr, float& Ci,
                                     float Br, float Bi,
                                     const float2* Zrow, int c) {
  float nr = 0.f, ni = 0.f;
  #pragma unroll
  for (int u = 0; u < 8; ++u) {
    int sb = ((u << 3) | c) << 2;
    float br = bpf(sb, Br), bi = bpf(sb, Bi);
    nr += Zrow[u].x*br - Zrow[u].y*bi;
    ni += Zrow[u].x*bi + Zrow[u].y*br;
  }
  Cr = nr; Ci = ni;
}

// ---------------------------------------------------------------------------
// Kernel A (solve): grid = B, 256 thr, 1 wg/CU.  R12's fused kernel MINUS
// the I_k stream: Taylor/Krylov front (wave-local Z, prefix-parallel
// powers), Frechet contraction, then writes ONLY I_b = M (16 KB/wg).
// The 67 MB I_k stream is delegated to kernel B -- session evidence (R4
// subtraction) shows a 16-wg/CU store kernel drains at ~4.8-5 TB/s vs the
// fused 1-wg/CU form's ~3.5 TB/s.
// ---------------------------------------------------------------------------
__global__ __launch_bounds__(256) void fi_solve(
    const void* __restrict__ xv,
    const void* __restrict__ kv,
    const void* __restrict__ bv,
    float* __restrict__ out, int Bn)
{
  const int i    = blockIdx.x;
  const int t    = threadIdx.x;        // 0..255
  const int wv   = t >> 6;             // wave id 0..3
  const int tl   = t & 63;             // lane within wave

  __shared__ float2 Tall[NTERM * TMAT];
  __shared__ float2 Rl[NTERM][8];
  __shared__ float2 Ql[8][8][8];
  __shared__ float  ampre[8], ampim[8], invPs[8];
  __shared__ __align__(16) float gk_km[64][8];  // g, k-major rows
  __shared__ __align__(16) float hk_t[8][68];   // h = g/P, p-major, padded

  const bool isdbl =
      (__ballot(!(fabsf(((const float*)xv)[tl]) < 1e6f)) != 0ull);

  // ---- phases 1-3, wave-local (all 4 waves, no barriers) ------------------
  float pwv = (float)rdin(bv, tl, isdbl);
  #pragma unroll
  for (int j = 0; j < 4; ++j)
    pwv += (float)rdin(xv, i*4 + j, isdbl) * (float)rdin(kv, j*64 + tl, isdbl);

  const int r = tl >> 3, c = tl & 7;
  float Zre, Zim;
  {
    int m = r ^ c;
    float hre = 0.f, him = 0.f;
    #pragma unroll
    for (int u = 0; u < 8; ++u) {
      int k = 0; float pr = 1.f, pim = 0.f;
      #pragma unroll
      for (int q = 0; q < 3; ++q) {
        int bit = 2 - q;
        int f  = (m >> bit) & 1;
        int ch = (u >> bit) & 1;
        int rb = (r >> bit) & 1;
        int d  = f ? (ch ? 2 : 1) : (ch ? 3 : 0);  // I=0,X=1,Y=2,Z=3
        k = (k << 2) | d;
        if (d == 2) {
          float nr = rb ? -pim : pim;
          float ni = rb ?  pr  : -pr;
          pr = nr; pim = ni;
        } else if (d == 3 && rb) { pr = -pr; pim = -pim; }
      }
      float w = bpf(k << 2, pwv);
      hre += w * pr; him += w * pim;
    }
    Zre = him; Zim = -hre;               // -i*(hre + i*him)
  }

  float2 Zrow[8];
  #pragma unroll
  for (int u = 0; u < 8; ++u) {
    int s = ((r << 3) | u) << 2;
    Zrow[u] = make_float2(bpf(s, Zre), bpf(s, Zim));
  }

  // prefix-parallel powers: wave w produces T_{5w}..T_{5w+4}
  float Z2r, Z2i; zmul(Z2r, Z2i, Zre, Zim, Zrow, c);   // Z^2 (all waves)
  if (wv == 0) {
    Tall[0*TMAT + r*TROW + c] = make_float2((r == c) ? 1.f : 0.f, 0.f);
    Tall[1*TMAT + r*TROW + c] = make_float2(Zre, Zim);
    Tall[2*TMAT + r*TROW + c] = make_float2(Z2r, Z2i);
    float cr_ = Z2r, ci_ = Z2i;
    #pragma unroll
    for (int s = 3; s < 5; ++s) {
      float nr_, ni_; zmul(nr_, ni_, cr_, ci_, Zrow, c);
      cr_ = nr_; ci_ = ni_;
      Tall[s*TMAT + r*TROW + c] = make_float2(cr_, ci_);
    }
  } else {
    float Z4r, Z4i; gmul(Z4r, Z4i, Z2r, Z2i, Z2r, Z2i, r, c);   // Z^4
    float Z5r, Z5i; zmul(Z5r, Z5i, Z4r, Z4i, Zrow, c);          // Z^5
    float Cr_, Ci_;
    if (wv == 1) { Cr_ = Z5r; Ci_ = Z5i; }
    else {
      float Z10r, Z10i; gmul(Z10r, Z10i, Z5r, Z5i, Z5r, Z5i, r, c);  // Z^10
      if (wv == 2) { Cr_ = Z10r; Ci_ = Z10i; }
      else         { gmul(Cr_, Ci_, Z10r, Z10i, Z5r, Z5i, r, c); }   // Z^15
    }
    const int base = wv * 5;
    Tall[base*TMAT + r*TROW + c] = make_float2(Cr_, Ci_);
    #pragma unroll
    for (int s = 1; s < 5; ++s) {
      float nr_, ni_; zmul(nr_, ni_, Cr_, Ci_, Zrow, c);
      Cr_ = nr_; Ci_ = ni_;
      Tall[(base + s)*TMAT + r*TROW + c] = make_float2(Cr_, Ci_);
    }
  }
  __syncthreads();

  // ---- phase 4: R_l[b] = sum_j A_j[b]/(j+l+1)!  and  psi, 1/P -------------
  if (t < NTERM * 8) {
    const int l = t >> 3, b = t & 7;
    float sr = 0.0f, si = 0.0f;
    #pragma unroll
    for (int j = 0; j < NTERM; ++j) {
      float cf = INVFACT[j + l + 1];
      float2 a = Tall[j*TMAT + b*TROW];          // A_j[b] = T_j[b][0]
      sr += cf * a.x; si += cf * a.y;
    }
    Rl[l][b] = make_float2(sr, si);
  }
  if (t >= 192 && t < 200) {                      // psi
    const int b = t - 192;
    float ar = 0.0f, ai = 0.0f;
    #pragma unroll
    for (int j = 0; j < NTERM; ++j) {
      float cf = INVFACT[j];
      float2 a = Tall[j*TMAT + b*TROW];
      ar += cf * a.x; ai += cf * a.y;
    }
    ampre[b] = ar; ampim[b] = ai;
    float P = ar*ar + ai*ai;
    invPs[b] = 1.0f / fmaxf(P, 1e-30f);
  }
  __syncthreads();

  // ---- phase 5: Q[p][a][b] = sum_l T_l[p,a] * R_l[b] ----------------------
  {
    const int p  = t >> 5;
    const int a  = (t >> 2) & 7;
    const int b0 = (t & 3) << 1;
    float q0r = 0.f, q0i = 0.f, q1r = 0.f, q1i = 0.f;
    #pragma unroll
    for (int l = 0; l < NTERM; ++l) {
      float2 T  = Tall[l*TMAT + p*TROW + a];
      f4_t  rp  = *(const f4_t*)&Rl[l][b0];
      q0r += T.x*rp.x - T.y*rp.y;  q0i += T.x*rp.y + T.y*rp.x;
      q1r += T.x*rp.z - T.y*rp.w;  q1i += T.x*rp.w + T.y*rp.z;
    }
    Ql[p][a][b0]   = make_float2(q0r, q0i);
    Ql[p][a][b0+1] = make_float2(q1r, q1i);
  }
  __syncthreads();

  // ---- phase 6: Jacobian, all 256 threads ---------------------------------
  {
    const int k  = t & 63;
    const int pg = t >> 6;
    const int p0 = pg << 1, p1 = p0 + 1;
    const int d0 = (k >> 4) & 3, d1 = (k >> 2) & 3, d2 = k & 3;
    const int m = ((((d0 == 1) | (d0 == 2)) ? 1 : 0) << 2)
                | ((((d1 == 1) | (d1 == 2)) ? 1 : 0) << 1)
                |  (((d2 == 1) | (d2 == 2)) ? 1 : 0);
    float S0r = 0.f, S0i = 0.f, S1r = 0.f, S1i = 0.f;
    #pragma unroll
    for (int a = 0; a < 8; ++a) {
      float pr = 1.0f, pim = 0.0f;
      const int dd[3] = {d0, d1, d2};
      #pragma unroll
      for (int q = 0; q < 3; ++q) {
        int rb = (a >> (2 - q)) & 1;
        int d = dd[q];
        if (d == 2) {
          float nr = rb ? -pim : pim;
          float ni = rb ?  pr  : -pr;
          pr = nr; pim = ni;
        } else if (d == 3 && rb) { pr = -pr; pim = -pim; }
      }
      const int b = a ^ m;
      float2 qa = Ql[p0][a][b];
      float2 qb = Ql[p1][a][b];
      S0r += pr*qa.x - pim*qa.y;  S0i += pr*qa.y + pim*qa.x;
      S1r += pr*qb.x - pim*qb.y;  S1i += pr*qb.y + pim*qb.x;
    }
    float g0 = 2.0f * (ampre[p0]*S0i - ampim[p0]*S0r);
    float g1 = 2.0f * (ampre[p1]*S1i - ampim[p1]*S1r);
    *(float2*)&gk_km[k][p0] = make_float2(g0, g1);
    hk_t[p0][k] = g0 * invPs[p0];
    hk_t[p1][k] = g1 * invPs[p1];
  }
  __syncthreads();

  // ---- I_b = M: contiguous 1KB per wave-instruction -----------------------
  const int m4 = (tl & 15) << 2;
  f4_t hv[8];
  #pragma unroll
  for (int p = 0; p < 8; ++p) hv[p] = *(const f4_t*)&hk_t[p][m4];
  {
    float* ob = out + (size_t)Bn * 65536 + (size_t)i * 4096;
    #pragma unroll
    for (int rr = 0; rr < 4; ++rr) {
      const int k = rr*16 + (t >> 4);    // (t>>4)*64 + (t&15)*4 == 4t
      const f4_t ga = *(const f4_t*)&gk_km[k][0];
      const f4_t gb = *(const f4_t*)&gk_km[k][4];
      f4_t acc = ga.x*hv[0] + ga.y*hv[1] + ga.z*hv[2] + ga.w*hv[3]
               + gb.x*hv[4] + gb.y*hv[5] + gb.z*hv[6] + gb.w*hv[7];
      *(f4_t*)(ob + (size_t)rr*1024 + (size_t)t*4) = acc;
    }
  }
}

// ---------------------------------------------------------------------------
// Kernel B (store): grid = 16*B, 256 thr -> 16 wg/CU churn (the config that
// drains writes at ~4.8-5 TB/s per R0/R4 evidence).  wg (i, blk) owns 16 KB:
// I_k[i, j=blk>>2, k in [(blk&3)*16, +16), :, :].  Reads its M-quarter from
// the I_b region (L2/L3-hot, written by fi_solve), stores contiguous 1KB
// per wave-instruction: iter it, wave wv -> wave-uniform M row kk=it*4+wv,
// lane tl covers floats 4tl..4tl+3 of the 1KB run (l = tl>>4, col=(tl&15)*4).
// ---------------------------------------------------------------------------
__global__ __launch_bounds__(256) void fi_store(
    const void* __restrict__ xv,
    float* __restrict__ out, int Bn)
{
  const int bx  = blockIdx.x;
  const int i   = bx >> 4;
  const int blk = bx & 15;             // j = blk>>2, k-quarter = blk&3
  const int t   = threadIdx.x;
  const int wv  = t >> 6;
  const int tl  = t & 63;

  __shared__ __align__(16) float Ms[16][68];

  const bool isdbl =
      (__ballot(!(fabsf(((const float*)xv)[tl]) < 1e6f)) != 0ull);

  // stage this block's M-quarter (16 rows x 64) into LDS
  const int rg = t >> 4;               // 0..15
  const int q4 = (t & 15) << 2;        // 0,4,..,60
  const float* Mg = out + (size_t)Bn * 65536 + (size_t)i * 4096;
  *(f4_t*)&Ms[rg][q4] =
      *(const f4_t*)(Mg + (size_t)(((blk & 3) << 4) + rg) * 64 + q4);

  // per-lane scale x[j] * x[l], l = tl>>4 (fixed per lane)
  const int j = blk >> 2;
  float sc;
  {
    float xj = (float)rdin(xv, i*4 + j, isdbl);
    sc = xj * (float)rdin(xv, i*4 + (tl >> 4), isdbl);
  }
  __syncthreads();

  float* ok = out + (size_t)i * 65536 + (size_t)blk * 4096;
  #pragma unroll
  for (int it = 0; it < 4; ++it) {
    const int kk = it*4 + wv;          // wave-uniform M row
    const f4_t mv = *(const f4_t*)&Ms[kk][q4];   // broadcast x4 across wave
    f4_t vv = sc * mv;
    // addr = (kk*4 + tl>>4)*64 + (tl&15)*4 = kk*256 + tl*4 -> 1KB contiguous
    *(f4_t*)(ok + (size_t)kk*256 + (size_t)tl*4) = vv;
  }
}

extern "C" void kernel_launch(void* const* d_in, const int* in_sizes, int n_in,
                              void* d_out, int out_size, void* d_ws, size_t ws_size,
                              hipStream_t stream) {
  (void)n_in; (void)d_ws; (void)ws_size; (void)out_size;
  int Bn = in_sizes[0] / 4;   // 256
  fi_solve<<<Bn, 256, 0, stream>>>(d_in[0], d_in[1], d_in[2], (float*)d_out, Bn);
  fi_store<<<Bn * 16, 256, 0, stream>>>(d_in[0], (float*)d_out, Bn);
}

// Round 14
// 91.913 us; speedup vs baseline: 1.0286x; 1.0286x over previous
//
#include <hip/hip_runtime.h>
#include <math.h>

typedef float f4_t __attribute__((ext_vector_type(4)));

#define NTERM 20           // Taylor powers T_0..T_19 of Z=-iH (||Z||<=4 -> err ~5e-7)
#define TROW  9            // padded row stride (float2) inside one T matrix
#define TMAT  (TROW * 8)   // float2 per stored matrix

// 1/n! table, compile-time (fp32; n>=34 underflows to 0).
__device__ const float INVFACT[48] = {
  1.0f, 1.0f, 5.0e-1f, 1.66666666666667e-1f, 4.16666666666667e-2f,
  8.33333333333333e-3f, 1.38888888888889e-3f, 1.98412698412698e-4f,
  2.48015873015873e-5f, 2.75573192239859e-6f, 2.75573192239859e-7f,
  2.50521083854417e-8f, 2.08767569878681e-9f, 1.60590438368216e-10f,
  1.14707455977297e-11f, 7.64716373181982e-13f, 4.77947733238738e-14f,
  2.81145725434552e-15f, 1.56192069685862e-16f, 8.22063524662433e-18f,
  4.11031762331216e-19f, 1.95729410633913e-20f, 8.89679139245057e-22f,
  3.86817017063068e-23f, 1.61173757109612e-24f, 6.44695028438447e-26f,
  2.47959626322480e-27f, 9.18368986379555e-29f, 3.27988923706984e-30f,
  1.13099628864477e-31f, 3.76998762881591e-33f, 1.21612504155352e-34f,
  3.80039075485474e-36f, 1.15163356207720e-37f, 3.38715753552116e-39f,
  0.f, 0.f, 0.f, 0.f, 0.f, 0.f, 0.f, 0.f, 0.f, 0.f, 0.f, 0.f, 0.f
};

__device__ __forceinline__ double rdin(const void* p, int idx, bool isdbl) {
  return isdbl ? ((const double*)p)[idx] : (double)((const float*)p)[idx];
}

__device__ __forceinline__ float bpf(int srcl, float v) {
  return __int_as_float(__builtin_amdgcn_ds_bpermute(srcl, __float_as_int(v)));
}

// C = A*B, 8x8 complex, lane-distributed (lane r*8+c holds element [r][c]).
__device__ __forceinline__ void gmul(float& Cr, float& Ci,
                                     float Ar, float Ai, float Br, float Bi,
                                     int r, int c) {
  float nr = 0.f, ni = 0.f;
  #pragma unroll
  for (int u = 0; u < 8; ++u) {
    int sa = ((r << 3) | u) << 2;
    int sb = ((u << 3) | c) << 2;
    float ar = bpf(sa, Ar), ai = bpf(sa, Ai);
    float br = bpf(sb, Br), bi = bpf(sb, Bi);
    nr += ar*br - ai*bi;
    ni += ar*bi + ai*br;
  }
  Cr = nr; Ci = ni;
}

// C = Z*B with Z's row cached in registers (Zrow[u] = Z[r][u]).
__device__ __forceinline__ void zmul(float& Cr, float& Ci,
                                     float Br, float Bi,
                                     const float2* Zrow, int c) {
  float nr = 0.f, ni = 0.f;
  #pragma unroll
  for (int u = 0; u < 8; ++u) {
    int sb = ((u << 3) | c) << 2;
    float br = bpf(sb, Br), bi = bpf(sb, Bi);
    nr += Zrow[u].x*br - Zrow[u].y*bi;
    ni += Zrow[u].x*bi + Zrow[u].y*br;
  }
  Cr = nr; Ci = ni;
}

// ---------------------------------------------------------------------------
// R14 = R12 verbatim (session best, 90.5us).  R13's two-kernel split
// regressed (+4us: launch + inter-kernel drain + M re-read exceed the
// 16-wg/CU drain-rate gain), closing the last structural question.  This
// fused 1-wg/CU form is the measured optimum of the explored space:
//   wave-local Z build (no barriers), prefix-parallel Krylov powers
//   (critical path 9 dependent matmuls across 4 SIMDs), exact Frechet
//   contraction, contiguous-1KB-per-wave-instruction stores.
// ---------------------------------------------------------------------------
__global__ __launch_bounds__(256) void fi_all(
    const void* __restrict__ xv,
    const void* __restrict__ kv,
    const void* __restrict__ bv,
    float* __restrict__ out, int Bn)
{
  const int i    = blockIdx.x;
  const int t    = threadIdx.x;        // 0..255
  const int wv   = t >> 6;             // wave id 0..3
  const int tl   = t & 63;             // lane within wave

  __shared__ float2 Tall[NTERM * TMAT];
  __shared__ float2 Rl[NTERM][8];
  __shared__ float2 Ql[8][8][8];
  __shared__ float  ampre[8], ampim[8], invPs[8];
  __shared__ __align__(16) float gk_km[64][8];  // g, k-major rows (b128-readable)
  __shared__ __align__(16) float hk_t[8][68];   // h = g/P, p-major, padded

  // ---- wave-parallel dtype sniff: lane tl checks word tl ------------------
  const bool isdbl =
      (__ballot(!(fabsf(((const float*)xv)[tl]) < 1e6f)) != 0ull);

  // ---- phases 1-3, wave-local (all 4 waves, no barriers) ------------------
  // pw in registers: lane k (=tl) holds pw_k
  float pwv = (float)rdin(bv, tl, isdbl);
  #pragma unroll
  for (int j = 0; j < 4; ++j)
    pwv += (float)rdin(xv, i*4 + j, isdbl) * (float)rdin(kv, j*64 + tl, isdbl);

  // Z = -iH from analytic Pauli strings, pw gathered via bpermute
  const int r = tl >> 3, c = tl & 7;
  float Zre, Zim;
  {
    int m = r ^ c;
    float hre = 0.f, him = 0.f;
    #pragma unroll
    for (int u = 0; u < 8; ++u) {
      int k = 0; float pr = 1.f, pim = 0.f;
      #pragma unroll
      for (int q = 0; q < 3; ++q) {
        int bit = 2 - q;
        int f  = (m >> bit) & 1;
        int ch = (u >> bit) & 1;
        int rb = (r >> bit) & 1;
        int d  = f ? (ch ? 2 : 1) : (ch ? 3 : 0);  // I=0,X=1,Y=2,Z=3
        k = (k << 2) | d;
        if (d == 2) {
          float nr = rb ? -pim : pim;
          float ni = rb ?  pr  : -pr;
          pr = nr; pim = ni;
        } else if (d == 3 && rb) { pr = -pr; pim = -pim; }
      }
      float w = bpf(k << 2, pwv);
      hre += w * pr; him += w * pim;
    }
    Zre = him; Zim = -hre;               // -i*(hre + i*him)
  }

  // Z row cache: Zrow[u] = Z[r][u]
  float2 Zrow[8];
  #pragma unroll
  for (int u = 0; u < 8; ++u) {
    int s = ((r << 3) | u) << 2;
    Zrow[u] = make_float2(bpf(s, Zre), bpf(s, Zim));
  }

  // prefix-parallel powers: wave w produces T_{5w}..T_{5w+4}
  float Z2r, Z2i; zmul(Z2r, Z2i, Zre, Zim, Zrow, c);   // Z^2 (all waves)
  if (wv == 0) {
    Tall[0*TMAT + r*TROW + c] = make_float2((r == c) ? 1.f : 0.f, 0.f);
    Tall[1*TMAT + r*TROW + c] = make_float2(Zre, Zim);
    Tall[2*TMAT + r*TROW + c] = make_float2(Z2r, Z2i);
    float cr_ = Z2r, ci_ = Z2i;
    #pragma unroll
    for (int s = 3; s < 5; ++s) {
      float nr_, ni_; zmul(nr_, ni_, cr_, ci_, Zrow, c);
      cr_ = nr_; ci_ = ni_;
      Tall[s*TMAT + r*TROW + c] = make_float2(cr_, ci_);
    }
  } else {
    float Z4r, Z4i; gmul(Z4r, Z4i, Z2r, Z2i, Z2r, Z2i, r, c);   // Z^4
    float Z5r, Z5i; zmul(Z5r, Z5i, Z4r, Z4i, Zrow, c);          // Z^5
    float Cr_, Ci_;
    if (wv == 1) { Cr_ = Z5r; Ci_ = Z5i; }
    else {
      float Z10r, Z10i; gmul(Z10r, Z10i, Z5r, Z5i, Z5r, Z5i, r, c);  // Z^10
      if (wv == 2) { Cr_ = Z10r; Ci_ = Z10i; }
      else         { gmul(Cr_, Ci_, Z10r, Z10i, Z5r, Z5i, r, c); }   // Z^15
    }
    const int base = wv * 5;
    Tall[base*TMAT + r*TROW + c] = make_float2(Cr_, Ci_);
    #pragma unroll
    for (int s = 1; s < 5; ++s) {
      float nr_, ni_; zmul(nr_, ni_, Cr_, Ci_, Zrow, c);
      Cr_ = nr_; Ci_ = ni_;
      Tall[(base + s)*TMAT + r*TROW + c] = make_float2(Cr_, Ci_);
    }
  }
  __syncthreads();

  // ---- phase 4: R_l[b] = sum_j A_j[b]/(j+l+1)!  and  psi, 1/P -------------
  if (t < NTERM * 8) {
    const int l = t >> 3, b = t & 7;
    float sr = 0.0f, si = 0.0f;
    #pragma unroll
    for (int j = 0; j < NTERM; ++j) {
      float cf = INVFACT[j + l + 1];
      float2 a = Tall[j*TMAT + b*TROW];          // A_j[b] = T_j[b][0]
      sr += cf * a.x; si += cf * a.y;
    }
    Rl[l][b] = make_float2(sr, si);
  }
  if (t >= 192 && t < 200) {                      // psi
    const int b = t - 192;
    float ar = 0.0f, ai = 0.0f;
    #pragma unroll
    for (int j = 0; j < NTERM; ++j) {
      float cf = INVFACT[j];
      float2 a = Tall[j*TMAT + b*TROW];
      ar += cf * a.x; ai += cf * a.y;
    }
    ampre[b] = ar; ampim[b] = ai;
    float P = ar*ar + ai*ai;
    invPs[b] = 1.0f / fmaxf(P, 1e-30f);
  }
  __syncthreads();

  // ---- phase 5: Q[p][a][b] = sum_l T_l[p,a] * R_l[b]  (all 256 threads) ---
  {
    const int p  = t >> 5;
    const int a  = (t >> 2) & 7;
    const int b0 = (t & 3) << 1;                 // even -> 16B-aligned Rl pair
    float q0r = 0.f, q0i = 0.f, q1r = 0.f, q1i = 0.f;
    #pragma unroll
    for (int l = 0; l < NTERM; ++l) {
      float2 T  = Tall[l*TMAT + p*TROW + a];
      f4_t  rp  = *(const f4_t*)&Rl[l][b0];      // {r0.re, r0.im, r1.re, r1.im}
      q0r += T.x*rp.x - T.y*rp.y;  q0i += T.x*rp.y + T.y*rp.x;
      q1r += T.x*rp.z - T.y*rp.w;  q1i += T.x*rp.w + T.y*rp.z;
    }
    Ql[p][a][b0]   = make_float2(q0r, q0i);
    Ql[p][a][b0+1] = make_float2(q1r, q1i);
  }
  __syncthreads();

  // ---- phase 6: Jacobian, all 256 threads (k = t&63, 2 p's per thread) ----
  {
    const int k  = t & 63;
    const int pg = t >> 6;               // p in {2pg, 2pg+1}
    const int p0 = pg << 1, p1 = p0 + 1;
    const int d0 = (k >> 4) & 3, d1 = (k >> 2) & 3, d2 = k & 3;
    const int m = ((((d0 == 1) | (d0 == 2)) ? 1 : 0) << 2)
                | ((((d1 == 1) | (d1 == 2)) ? 1 : 0) << 1)
                |  (((d2 == 1) | (d2 == 2)) ? 1 : 0);
    float S0r = 0.f, S0i = 0.f, S1r = 0.f, S1i = 0.f;
    #pragma unroll
    for (int a = 0; a < 8; ++a) {
      float pr = 1.0f, pim = 0.0f;               // phi_k(a) in {+-1, +-i}
      const int dd[3] = {d0, d1, d2};
      #pragma unroll
      for (int q = 0; q < 3; ++q) {
        int rb = (a >> (2 - q)) & 1;
        int d = dd[q];
        if (d == 2) {
          float nr = rb ? -pim : pim;
          float ni = rb ?  pr  : -pr;
          pr = nr; pim = ni;
        } else if (d == 3 && rb) { pr = -pr; pim = -pim; }
      }
      const int b = a ^ m;
      float2 qa = Ql[p0][a][b];
      float2 qb = Ql[p1][a][b];
      S0r += pr*qa.x - pim*qa.y;  S0i += pr*qa.y + pim*qa.x;
      S1r += pr*qb.x - pim*qb.y;  S1i += pr*qb.y + pim*qb.x;
    }
    // dpsi = -i*S ;  g = 2 Re(conj(psi)*dpsi) = 2(psi_re*Si - psi_im*Sr)
    float g0 = 2.0f * (ampre[p0]*S0i - ampim[p0]*S0r);
    float g1 = 2.0f * (ampre[p1]*S1i - ampim[p1]*S1r);
    *(float2*)&gk_km[k][p0] = make_float2(g0, g1);   // k-major row
    hk_t[p0][k] = g0 * invPs[p0];
    hk_t[p1][k] = g1 * invPs[p1];
  }

  // per-thread scales x[jj]*x[l] (l = tl>>4), loaded before the barrier
  float sc[4];
  {
    float xl = (float)rdin(xv, i*4 + (tl >> 4), isdbl);
    #pragma unroll
    for (int jj = 0; jj < 4; ++jj)
      sc[jj] = xl * (float)rdin(xv, i*4 + jj, isdbl);
  }
  __syncthreads();

  // ---- phase 7: contiguous-1KB-per-wave-instruction stores ----------------
  // hoisted h fragments: column block (tl&15)*4, fixed per thread
  const int m4 = (tl & 15) << 2;
  f4_t hv[8];
  #pragma unroll
  for (int p = 0; p < 8; ++p) hv[p] = *(const f4_t*)&hk_t[p][m4];

  // I_k: wave-uniform row k = it*4 + wv; acc computed ONCE per k, 4 scaled
  // j-copies issued from it.  Lane tl writes floats 4tl..4tl+3 of each
  // contiguous 256-float run I_k[i, jj, k, :, :].
  {
    float* ok = out + (size_t)i * 65536;
    #pragma unroll
    for (int it = 0; it < 16; ++it) {
      const int k = it*4 + wv;
      const f4_t ga = *(const f4_t*)&gk_km[k][0];
      const f4_t gb = *(const f4_t*)&gk_km[k][4];
      f4_t acc = ga.x*hv[0] + ga.y*hv[1] + ga.z*hv[2] + ga.w*hv[3]
               + gb.x*hv[4] + gb.y*hv[5] + gb.z*hv[6] + gb.w*hv[7];
      #pragma unroll
      for (int jj = 0; jj < 4; ++jj) {
        f4_t vv = sc[jj] * acc;
        *(f4_t*)(ok + (size_t)jj*16384 + (size_t)k*256 + (size_t)tl*4) = vv;
      }
    }
  }

  // I_b: addr = r*1024 + 4t -> contiguous 1KB per wave-instruction
  {
    float* ob = out + (size_t)Bn * 65536 + (size_t)i * 4096;
    #pragma unroll
    for (int rr = 0; rr < 4; ++rr) {
      const int k = rr*16 + (t >> 4);    // (t>>4)*64 + (t&15)*4 == 4t
      const f4_t ga = *(const f4_t*)&gk_km[k][0];
      const f4_t gb = *(const f4_t*)&gk_km[k][4];
      f4_t acc = ga.x*hv[0] + ga.y*hv[1] + ga.z*hv[2] + ga.w*hv[3]
               + gb.x*hv[4] + gb.y*hv[5] + gb.z*hv[6] + gb.w*hv[7];
      *(f4_t*)(ob + (size_t)rr*1024 + (size_t)t*4) = acc;
    }
  }
}

extern "C" void kernel_launch(void* const* d_in, const int* in_sizes, int n_in,
                              void* d_out, int out_size, void* d_ws, size_t ws_size,
                              hipStream_t stream) {
  (void)n_in; (void)d_ws; (void)ws_size; (void)out_size;
  int Bn = in_sizes[0] / 4;   // 256
  fi_all<<<Bn, 256, 0, stream>>>(d_in[0], d_in[1], d_in[2], (float*)d_out, Bn);
}